// Round 5
// baseline (123.624 us; speedup 1.0000x reference)
//
#include <hip/hip_runtime.h>
#include <hip/hip_bf16.h>

typedef __attribute__((ext_vector_type(8))) short short8;
typedef __attribute__((ext_vector_type(4))) float floatx4;

#define NROWS 4096
#define NHALF 2048
#define DDIM  128
#define SQRT_SCALE 2.6857914f     // sqrt(1/(0.2*ln2)); dot of stored z == (sim/T)*log2(e)
#define LN2 0.69314718056f

// ws float layout: [0]=loss acc, [1]=all_num, [2]=sync counter, [3]=final counter,
// rowpart [64, +8*16384), diag [131136, +16384), pos [147520, +16384), z after.
#define WS_ROWPART_OFF 64
#define WS_DIAG_OFF   131136
#define WS_POS_OFF    147520
#define WS_Z_BYTE_OFF 655616      // (147520+16384)*4, 16B aligned

__device__ inline unsigned short f2bf(float f) {
    unsigned u = __builtin_bit_cast(unsigned, f);
    u += 0x7fffu + ((u >> 16) & 1u);          // RNE
    return (unsigned short)(u >> 16);
}

// ---------------- kernel 1: normalize + scale + cast to bf16; all_num; zero counters -------
// 2049 blocks: 2048 x 8 rows (float4/lane, 32 lanes per row), block 2048 does jv sum.
__global__ __launch_bounds__(256) void k_norm(const float* __restrict__ emb_i,
                                              const float* __restrict__ emb_j,
                                              const float* __restrict__ jv,
                                              float* __restrict__ wsf,
                                              unsigned short* __restrict__ z) {
    int bx = blockIdx.x, tid = threadIdx.x;
    if (bx == 2048) {                         // all_num = sum(joint_valid)
        __shared__ float sred[256];
        float s = 0.f;
        #pragma unroll
        for (int i = 0; i < 8; ++i) s += jv[tid + 256 * i];
        sred[tid] = s; __syncthreads();
        for (int off = 128; off > 0; off >>= 1) {
            if (tid < off) sred[tid] += sred[tid + off];
            __syncthreads();
        }
        if (tid == 0) wsf[1] = sred[0];
        return;
    }
    if (bx == 0 && tid == 0) {                // zero loss acc + both counters (ws poisoned)
        wsf[0] = 0.f; wsf[2] = 0.f; wsf[3] = 0.f;
    }

    int wave = tid >> 6, lane = tid & 63, half = lane >> 5, sl = lane & 31;
    int r = bx * 8 + wave * 2 + half;         // global row 0..16383
    int l = r >> 12, n = r & 4095;
    const float* src = (n < NHALF) ? (emb_i + ((size_t)l * NHALF + n) * DDIM)
                                   : (emb_j + ((size_t)l * NHALF + (n - NHALF)) * DDIM);
    float4 v = *(const float4*)(src + sl * 4);
    float ss = v.x * v.x + v.y * v.y + v.z * v.z + v.w * v.w;
    #pragma unroll
    for (int off = 1; off < 32; off <<= 1) ss += __shfl_xor(ss, off);  // within 32-lane half
    float inv = SQRT_SCALE / fmaxf(sqrtf(ss), 1e-12f);
    unsigned p0 = ((unsigned)f2bf(v.y * inv) << 16) | (unsigned)f2bf(v.x * inv);
    unsigned p1 = ((unsigned)f2bf(v.w * inv) << 16) | (unsigned)f2bf(v.z * inv);
    *(uint2*)(z + (size_t)r * DDIM + sl * 4) = (uint2){p0, p1};
}

// ---------------- kernel 2: fused sim + loss + final (one dispatch) ------------------------
// Phase 1 (all 512 blocks): LDS-free streaming sim, 64 rows/wave, B paired-step double-
//   buffered from global (L2-resident). Plain stores to rowpart/diag/pos.
// Handshake: release-increment counter. Deadlock-free: blocks >=64 exit after increment,
//   so the counter reaches 512 regardless of scheduling/residency.
// Phase 2 (blocks 0..63): acquire-spin to 512, then per-row loss; last finisher writes out.
__global__ __launch_bounds__(256) void k_simloss(const unsigned short* __restrict__ z,
                                                 float* __restrict__ wsf,
                                                 const float* __restrict__ jv,
                                                 float* __restrict__ out) {
    float* rowpart = wsf + WS_ROWPART_OFF;
    float* diag    = wsf + WS_DIAG_OFF;
    float* pos     = wsf + WS_POS_OFF;
    unsigned* cnt  = (unsigned*)&wsf[2];
    unsigned* cnt2 = (unsigned*)&wsf[3];

    int bx = blockIdx.x, tid = threadIdx.x;
    int l = bx & 3, rb = (bx >> 2) & 15, cg = bx >> 6;
    int wave = tid >> 6, lane = tid & 63, m = lane & 15, quad = lane >> 4;
    const unsigned short* zl = z + (size_t)l * NROWS * DDIM;
    int l4 = l * NROWS;
    int R0 = rb * 256 + wave * 64;            // wave's row base (local to l)
    int C0 = cg * 512;                        // block's col base

    short8 a[4][4];                           // 4 row-subtiles x 4 k-steps, resident
    #pragma unroll
    for (int rs = 0; rs < 4; ++rs) {
        const unsigned short* p = zl + (size_t)(R0 + rs * 16 + m) * DDIM + quad * 8;
        #pragma unroll
        for (int kk = 0; kk < 4; ++kk) a[rs][kk] = *(const short8*)(p + kk * 32);
    }
    floatx4 rsum[4];
    #pragma unroll
    for (int rs = 0; rs < 4; ++rs) rsum[rs] = (floatx4){0.f, 0.f, 0.f, 0.f};

    auto simstep = [&](short8* B, int cs_) {
        int c0 = C0 + cs_ * 16;               // tile col base (wave-uniform)
        #pragma unroll
        for (int rs = 0; rs < 4; ++rs) {
            floatx4 acc = (floatx4){0.f, 0.f, 0.f, 0.f};
            acc = __builtin_amdgcn_mfma_f32_16x16x32_bf16(a[rs][0], B[0], acc, 0, 0, 0);
            acc = __builtin_amdgcn_mfma_f32_16x16x32_bf16(a[rs][1], B[1], acc, 0, 0, 0);
            acc = __builtin_amdgcn_mfma_f32_16x16x32_bf16(a[rs][2], B[2], acc, 0, 0, 0);
            acc = __builtin_amdgcn_mfma_f32_16x16x32_bf16(a[rs][3], B[3], acc, 0, 0, 0);
            int rbase = R0 + rs * 16;
            if (c0 == rbase || c0 == (rbase ^ 2048)) {  // rare, wave-uniform
                int c = m - (quad << 2);      // lane holds (row=rbase+m) iff quad*4+c == m
                if (c >= 0 && c < 4)
                    ((c0 == rbase) ? diag : pos)[l4 + rbase + m] = acc[c];
            }
            rsum[rs][0] += __builtin_amdgcn_exp2f(acc[0]);
            rsum[rs][1] += __builtin_amdgcn_exp2f(acc[1]);
            rsum[rs][2] += __builtin_amdgcn_exp2f(acc[2]);
            rsum[rs][3] += __builtin_amdgcn_exp2f(acc[3]);
        }
    };

    const unsigned short* bp = zl + (size_t)(C0 + m) * DDIM + quad * 8;
    short8 bA[4], bB[4];
    #pragma unroll
    for (int k = 0; k < 4; ++k) bA[k] = *(const short8*)(bp + k * 32);

    for (int cs = 0; cs < 32; cs += 2) {      // paired-step: no register moves
        const unsigned short* q1 = bp + (size_t)(cs + 1) * (16 * DDIM);
        #pragma unroll
        for (int k = 0; k < 4; ++k) bB[k] = *(const short8*)(q1 + k * 32);
        simstep(bA, cs);
        if (cs + 2 < 32) {
            const unsigned short* q2 = bp + (size_t)(cs + 2) * (16 * DDIM);
            #pragma unroll
            for (int k = 0; k < 4; ++k) bA[k] = *(const short8*)(q2 + k * 32);
        }
        simstep(bB, cs + 1);
    }

    // row-sums: reduce across the 16 column-lanes (bits 0..3 of lane)
    #pragma unroll
    for (int off = 1; off < 16; off <<= 1)
        #pragma unroll
        for (int rs = 0; rs < 4; ++rs)
            #pragma unroll
            for (int c = 0; c < 4; ++c)
                rsum[rs][c] += __shfl_xor(rsum[rs][c], off);
    if (m == 0) {                             // plain stores: unique (cg,row) per value
        #pragma unroll
        for (int rs = 0; rs < 4; ++rs)
            #pragma unroll
            for (int c = 0; c < 4; ++c) {
                int rg = R0 + rs * 16 + quad * 4 + c;
                rowpart[cg * 16384 + l4 + rg] = rsum[rs][c];
            }
    }

    // ---- handshake ----
    __syncthreads();                          // all waves' stores issued
    if (tid == 0) {
        __threadfence();                      // drain stores to device scope
        __hip_atomic_fetch_add(cnt, 1u, __ATOMIC_RELEASE, __HIP_MEMORY_SCOPE_AGENT);
    }
    if (bx >= 64) return;                     // exiting blocks free their CUs -> no deadlock

    if (tid == 0) {
        while (__hip_atomic_load(cnt, __ATOMIC_ACQUIRE, __HIP_MEMORY_SCOPE_AGENT) < 512u)
            __builtin_amdgcn_s_sleep(8);
    }
    __syncthreads();
    __threadfence();                          // order subsequent loads after the acquire

    // ---- loss phase: rows bx*256 + tid ----
    __shared__ float sred[256];
    int r = bx * 256 + tid;
    int n = r & 4095;
    float tot = 0.f;
    #pragma unroll
    for (int g = 0; g < 8; ++g) tot += rowpart[g * 16384 + r];
    float denom = tot - __builtin_amdgcn_exp2f(diag[r]);   // exact cancel of diagonal term
    float contrib = LN2 * (__builtin_amdgcn_logf(denom) - pos[r]);
    float local = contrib * jv[n & (NHALF - 1)];
    sred[tid] = local; __syncthreads();
    for (int off = 128; off > 0; off >>= 1) {
        if (tid < off) sred[tid] += sred[tid + off];
        __syncthreads();
    }
    if (tid == 0) {
        atomicAdd(&wsf[0], sred[0]);
        __threadfence();
        unsigned old = __hip_atomic_fetch_add(cnt2, 1u, __ATOMIC_ACQ_REL,
                                              __HIP_MEMORY_SCOPE_AGENT);
        if (old == 63u) {                     // last finisher: all 64 partials are in
            float s = atomicAdd(&wsf[0], 0.f);   // coherent read of the accumulated loss
            out[0] = s / (2.f * wsf[1]);
        }
    }
}

extern "C" void kernel_launch(void* const* d_in, const int* in_sizes, int n_in,
                              void* d_out, int out_size, void* d_ws, size_t ws_size,
                              hipStream_t stream) {
    const float* emb_i = (const float*)d_in[0];
    const float* emb_j = (const float*)d_in[1];
    const float* jv    = (const float*)d_in[2];
    float* wsf = (float*)d_ws;
    unsigned short* z = (unsigned short*)((char*)d_ws + WS_Z_BYTE_OFF);
    float* out = (float*)d_out;

    k_norm   <<<2049, 256, 0, stream>>>(emb_i, emb_j, jv, wsf, z);
    k_simloss<<<512,  256, 0, stream>>>(z, wsf, jv, out);
}